// Round 8
// baseline (305.311 us; speedup 1.0000x reference)
//
#include <hip/hip_runtime.h>
#include <hip/hip_bf16.h>

// SelfAttention: x[8,256,48,48] fp32; wq/wk/wv[256,256] fp32.
// out = x + attn(softmax(q^T k), v). B=8, C=256, N=2304. fp16 MFMA path.
//
// R7 post-mortem: acc(128 AGPR)+d(16 AGPR)+128 VGPR = 272 unified regs > 256
// -> 1 wave/SIMD (Occupancy 12.8%), everything latency-exposed.
// R8: 2-way channel split. Block = 4 waves = 2 q-tiles x 2 c-halves.
// Each wave: full-C QK^T (S duplicated per c-half pair, +21.7GF ~ cheap),
// PV/acc only for 128 channels -> acc 64 AGPR, total ~194 regs -> 2.5 w/SIMD.
// QK^T as 2 independent 8-MFMA chains (halved dep latency).
//
// K_swz[kb][ks 16][hi 2][key 32][j 8]: short off = kb*8192+ks*512+hi*256+key*8+j
//   holds K[key of chunk kb][c = 16ks+8hi+j]   (A-frag for QK^T)
// V_swz[kb][ct 8][kh 2][hi 2][c 32][j 8]: off = kb*8192+ct*1024+kh*512+hi*256+c*8+j
//   holds V[c = 32ct+cloc][key = 16kh+8hi+j]   (A-frag = V^T for PV)
// ws: wq/wk/wv fp16 [65536 ea]; Qt [B*N*C] token-major; Ksw,Vsw [B*N*C];
//     P fp16 [splits][B][C][N] (per-split normalized O_s); ml f32 [splits][B][N][2].

#define DEVI __device__ __forceinline__

typedef _Float16 f16x8 __attribute__((ext_vector_type(8)));
typedef float f32x4 __attribute__((ext_vector_type(4)));
typedef float f32x16 __attribute__((ext_vector_type(16)));

constexpr int Bn = 8, Cn = 256, Nn = 48 * 48;   // 2304

DEVI unsigned short f2h(float f) {
  _Float16 h = (_Float16)f;
  return __builtin_bit_cast(unsigned short, h);
}
DEVI float h2f(unsigned short u) {
  return (float)__builtin_bit_cast(_Float16, u);
}
DEVI unsigned pk2(float a, float b) {           // pack 2 f32 -> f16x2 (RTZ)
  auto h = __builtin_amdgcn_cvt_pkrtz(a, b);
  return __builtin_bit_cast(unsigned, h);
}

#define MFMA16(a, b, c) __builtin_amdgcn_mfma_f32_16x16x32_f16((a), (b), (c), 0, 0, 0)
#define MFMA32(a, b, c) __builtin_amdgcn_mfma_f32_32x32x16_f16((a), (b), (c), 0, 0, 0)

__global__ __launch_bounds__(256) void cvt_w(const float* __restrict__ wq,
                                             const float* __restrict__ wk,
                                             const float* __restrict__ wv,
                                             unsigned short* __restrict__ o) {
  int idx = blockIdx.x * 256 + threadIdx.x;     // 3*65536 total
  const float* s = (idx < Cn * Cn) ? wq : (idx < 2 * Cn * Cn) ? wk : wv;
  o[idx] = f2h(s[idx & (Cn * Cn - 1)]);
}

// ---------------- QKV projection ----------------
// grid (N/64, B, 3), 256 thr (4 waves, 16 tokens each). z: 0=Q 1=K 2=V.
// 16x16x32 frags: A/B lane l: row/col=l&15, k=8*(l>>4)+j. C/D: col=l&15, row=4*(l>>4)+r.
__global__ __launch_bounds__(256) void qkv_proj(
    const float* __restrict__ x,
    const unsigned short* __restrict__ wqb, const unsigned short* __restrict__ wkb,
    const unsigned short* __restrict__ wvb,
    unsigned short* __restrict__ Qt, unsigned short* __restrict__ Ksw,
    unsigned short* __restrict__ Vsw) {
  __shared__ unsigned short xT[64][264];        // [token][c], +8 pad
  const int tid = threadIdx.x;
  const int n0 = blockIdx.x * 64;
  const int b = blockIdx.y;
  const int z = blockIdx.z;
  const float* xb = x + (size_t)b * Cn * Nn;
  {
    int cbase = tid >> 4;
    int nn = (tid & 15) * 4;
#pragma unroll
    for (int it = 0; it < 16; ++it) {
      int c = cbase + 16 * it;
      float4 v = *(const float4*)(xb + (size_t)c * Nn + n0 + nn);
      xT[nn + 0][c] = f2h(v.x);
      xT[nn + 1][c] = f2h(v.y);
      xT[nn + 2][c] = f2h(v.z);
      xT[nn + 3][c] = f2h(v.w);
    }
  }
  __syncthreads();
  const int lane = tid & 63, w = tid >> 6;
  const int i = lane & 15, g = lane >> 4;
  f16x8 xf[8];                                  // x^T frags
#pragma unroll
  for (int ks = 0; ks < 8; ++ks)
    xf[ks] = *(const f16x8*)(&xT[w * 16 + i][32 * ks + 8 * g]);

  const int kb0 = (n0 >> 5) + (w >> 1);         // 32-token chunk id
  if (z == 0) {                                 // Q -> token-major [N][C]
    const size_t tokbase = (size_t)b * Nn + n0 + w * 16;
    for (int ot = 0; ot < 16; ++ot) {
      f32x4 acc = {0.f, 0.f, 0.f, 0.f};
      const unsigned short* wr = wqb + (ot * 16 + i) * Cn + 8 * g;
#pragma unroll
      for (int ks = 0; ks < 8; ++ks)
        acc = MFMA16(xf[ks], *(const f16x8*)(wr + 32 * ks), acc);
#pragma unroll
      for (int r = 0; r < 4; ++r)
        Qt[(tokbase + 4 * g + r) * Cn + ot * 16 + i] = f2h(acc[r]);
    }
  } else if (z == 1) {                          // K -> frag-swizzled
    // acc[r] = K[tok = n0+w16+4g+r][c = ot*16+i]
    unsigned short* kout = Ksw + (size_t)b * Nn * Cn + (size_t)kb0 * 8192
                         + ((i >> 3) & 1) * 256 + (i & 7);
    const int keyb = (w & 1) * 16 + 4 * g;      // + r
    for (int ot = 0; ot < 16; ++ot) {
      f32x4 acc = {0.f, 0.f, 0.f, 0.f};
      const unsigned short* wr = wkb + (ot * 16 + i) * Cn + 8 * g;
#pragma unroll
      for (int ks = 0; ks < 8; ++ks)
        acc = MFMA16(xf[ks], *(const f16x8*)(wr + 32 * ks), acc);
#pragma unroll
      for (int r = 0; r < 4; ++r)
        kout[ot * 512 + (keyb + r) * 8] = f2h(acc[r]);
    }
  } else {                                      // V -> frag-swizzled (V^T A-frags)
    // acc[r] = V[c = ot*16+4g+r][tok = n0+w16+i]
    unsigned short* vout = Vsw + (size_t)b * Nn * Cn + (size_t)kb0 * 8192
                         + (w & 1) * 512 + ((i >> 3) & 1) * 256 + (i & 7);
    for (int ot = 0; ot < 16; ++ot) {
      f32x4 acc = {0.f, 0.f, 0.f, 0.f};
      const unsigned short* wr = wvb + (ot * 16 + i) * Cn + 8 * g;
#pragma unroll
      for (int ks = 0; ks < 8; ++ks)
        acc = MFMA16(*(const f16x8*)(wr + 32 * ks), xf[ks], acc);
#pragma unroll
      for (int r = 0; r < 4; ++r) {
        int c = ot * 16 + 4 * g + r;
        vout[(c >> 5) * 1024 + (c & 31) * 8] = f2h(acc[r]);
      }
    }
  }
}

// ---------------- flash attention, split-K, c-split, register-direct -------
// grid Bn*splits*36, 256 thr = 4 waves = 2 q-tiles(32q) x 2 c-halves(128c).
// Swapped S = mfma32(Kfrag, Qfrag): lane query=l&31, keys (r&3)+8(r>>2)+4hi.
// Each wave: full-C QK^T + softmax (duplicated per c-half pair), PV for its
// 128 channels. Writes O_s = acc/l_s as fp16 P[s][b][c][n]; ml={m,l} f32.
__global__ __launch_bounds__(256, 2) void attn_split(
    const unsigned short* __restrict__ Qt, const unsigned short* __restrict__ Ksw,
    const unsigned short* __restrict__ Vsw,
    unsigned short* __restrict__ P, float* __restrict__ ml, int splits) {
  const int nblk = gridDim.x;                   // divisible by 8
  const int cpx = nblk >> 3;
  const int swz = (blockIdx.x & 7) * cpx + (blockIdx.x >> 3);  // XCD chunked
  const int per_b = splits * 36;
  const int b = swz / per_b;
  const int rem = swz - b * per_b;
  const int s = rem / 36;
  const int qt = rem - s * 36;
  const int n0 = qt * 64;
  const int kn = Nn / splits, k0 = s * kn;

  const int tid = threadIdx.x, lane = tid & 63, w = tid >> 6;
  const int q = lane & 31, hi = lane >> 5;
  const int qtile = w & 1, chalf = w >> 1;
  const int q0 = n0 + qtile * 32;

  // resident Q B-frags: lane: query=q, c = 16*ks + 8*hi + j
  const unsigned short* Qb = Qt + ((size_t)b * Nn + q0 + q) * Cn + 8 * hi;
  f16x8 qf[16];
#pragma unroll
  for (int ks = 0; ks < 16; ++ks) qf[ks] = *(const f16x8*)(Qb + 16 * ks);

  f32x16 acc[4];                                // channels chalf*128 .. +128
#pragma unroll
  for (int ct = 0; ct < 4; ++ct) acc[ct] = (f32x16)(0.f);
  float m = -1e30f, lsum = 0.f;

  const unsigned short* Kb = Ksw + (size_t)b * Nn * Cn + hi * 256 + q * 8;
  const unsigned short* Vb = Vsw + (size_t)b * Nn * Cn + hi * 256 + q * 8;

  for (int jc = 0; jc < kn; jc += 32) {
    const size_t kb = (size_t)((k0 + jc) >> 5) * 8192;
    // ---- QK^T: d[key][query], 2 independent 8-MFMA chains over c=256 ----
    const unsigned short* kp = Kb + kb;
    f32x16 da = (f32x16)(0.f), db = (f32x16)(0.f);
#pragma unroll
    for (int ks = 0; ks < 8; ++ks) {
      da = MFMA32(*(const f16x8*)(kp + ks * 512), qf[ks], da);
      db = MFMA32(*(const f16x8*)(kp + (ks + 8) * 512), qf[ks + 8], db);
    }
    f32x16 d = da + db;

    // ---- online softmax: lane owns query q, 16 scores ----
    float mx = d[0];
#pragma unroll
    for (int r = 1; r < 16; ++r) mx = fmaxf(mx, d[r]);
    mx = fmaxf(mx, __shfl_xor(mx, 32));         // full 32-key max
    if (__any(mx > m + 8.f)) {                  // defer-max (THR=8)
      float mnew = fmaxf(m, mx);
      float alpha = __expf(m - mnew);
      m = mnew;
      lsum *= alpha;
#pragma unroll
      for (int ct = 0; ct < 4; ++ct)
#pragma unroll
        for (int r = 0; r < 16; ++r) acc[ct][r] *= alpha;
    }
    float p[16];
#pragma unroll
    for (int r = 0; r < 16; ++r) p[r] = __expf(d[r] - m);
    float cs = 0.f;
#pragma unroll
    for (int r = 0; r < 16; ++r) cs += p[r];
    cs += __shfl_xor(cs, 32);
    lsum += cs;

    // ---- P -> B-frags (keys 0..15 | 16..31), half-wave exchange ----
    unsigned A0 = pk2(p[0], p[1]), A1 = pk2(p[2], p[3]);
    unsigned A2 = pk2(p[4], p[5]), A3 = pk2(p[6], p[7]);
    unsigned A4 = pk2(p[8], p[9]), A5 = pk2(p[10], p[11]);
    unsigned A6 = pk2(p[12], p[13]), A7 = pk2(p[14], p[15]);
    unsigned s0 = __shfl_xor(A0, 32), s1 = __shfl_xor(A1, 32);
    unsigned s2 = __shfl_xor(A2, 32), s3 = __shfl_xor(A3, 32);
    unsigned s4 = __shfl_xor(A4, 32), s5 = __shfl_xor(A5, 32);
    unsigned s6 = __shfl_xor(A6, 32), s7 = __shfl_xor(A7, 32);
    union { unsigned u[4]; f16x8 v; } pb0, pb1;
    pb0.u[0] = hi ? s2 : A0;  pb0.u[1] = hi ? s3 : A1;
    pb0.u[2] = hi ? A2 : s0;  pb0.u[3] = hi ? A3 : s1;
    pb1.u[0] = hi ? s6 : A4;  pb1.u[1] = hi ? s7 : A5;
    pb1.u[2] = hi ? A6 : s4;  pb1.u[3] = hi ? A7 : s5;

    // ---- PV: 4 c-tiles of this wave's c-half; contiguous V^T frag loads ----
    const unsigned short* vp = Vb + kb;
#pragma unroll
    for (int ct = 0; ct < 4; ++ct) {
      const int ctg = chalf * 4 + ct;
      acc[ct] = MFMA32(*(const f16x8*)(vp + ctg * 1024), pb0.v, acc[ct]);
      acc[ct] = MFMA32(*(const f16x8*)(vp + ctg * 1024 + 512), pb1.v, acc[ct]);
    }
  }

  // ---- epilogue: O_s = acc/lsum -> fp16; c = 32ctg + (r&3)+8*(r>>2)+4hi ----
  const float rl = 1.f / lsum;
  unsigned short* Pb = P + (size_t)(s * Bn + b) * Cn * Nn;
#pragma unroll
  for (int ct = 0; ct < 4; ++ct)
#pragma unroll
    for (int r = 0; r < 16; ++r) {
      int c = 32 * (chalf * 4 + ct) + (r & 3) + 8 * (r >> 2) + 4 * hi;
      Pb[(size_t)c * Nn + q0 + q] = f2h(acc[ct][r] * rl);
    }
  if (!hi && !chalf)
    *(float2*)&ml[((size_t)(s * Bn + b) * Nn + q0 + q) * 2] = make_float2(m, lsum);
}

// ---------------- combine partials + residual ----------------
// out = x + sum_s w_s * O_s,  w_s = exp(m_s - M) * l_s / sum(exp(m_s-M) l_s).
__global__ __launch_bounds__(256) void combine_k(
    const float* __restrict__ x, const unsigned short* __restrict__ P,
    const float* __restrict__ ml, float* __restrict__ out, int splits) {
  __shared__ float sc[4][32];
  const int tpb = Nn / 32;                      // 72
  const int b = blockIdx.x / tpb;
  const int n0 = (blockIdx.x - b * tpb) * 32;
  const int t = threadIdx.x;
  if (t < 32) {
    const int n = n0 + t;
    const size_t sstr = (size_t)Bn * Nn * 2;
    const float* mlb = ml + ((size_t)b * Nn + n) * 2;
    float m0 = mlb[0], l0 = mlb[1];
    float m1 = -1e30f, l1 = 0.f, m2 = -1e30f, l2 = 0.f, m3 = -1e30f, l3 = 0.f;
    if (splits > 1) { m1 = mlb[sstr]; l1 = mlb[sstr + 1]; }
    if (splits > 2) { m2 = mlb[2 * sstr]; l2 = mlb[2 * sstr + 1]; }
    if (splits > 3) { m3 = mlb[3 * sstr]; l3 = mlb[3 * sstr + 1]; }
    float M = fmaxf(fmaxf(m0, m1), fmaxf(m2, m3));
    float g0 = __expf(m0 - M) * l0, g1 = __expf(m1 - M) * l1;
    float g2 = __expf(m2 - M) * l2, g3 = __expf(m3 - M) * l3;
    float rden = 1.f / (g0 + g1 + g2 + g3);
    sc[0][t] = g0 * rden; sc[1][t] = g1 * rden;
    sc[2][t] = g2 * rden; sc[3][t] = g3 * rden;
  }
  __syncthreads();
  const int nl4 = (t & 7) * 4, c0 = t >> 3;
  const size_t pstr = (size_t)Bn * Cn * Nn;     // shorts per split
  const float* xb = x + (size_t)b * Cn * Nn;
  float* ob = out + (size_t)b * Cn * Nn;
#pragma unroll
  for (int k = 0; k < 8; ++k) {
    const int c = c0 + 32 * k;
    const unsigned short* Pp = P + ((size_t)b * Cn + c) * Nn + n0 + nl4;
    f32x4 a = {0.f, 0.f, 0.f, 0.f};
    for (int s2 = 0; s2 < splits; ++s2) {
      ushort4 ph = *(const ushort4*)(Pp + s2 * pstr);
      f32x4 pv = {h2f(ph.x), h2f(ph.y), h2f(ph.z), h2f(ph.w)};
      f32x4 sw = {sc[s2][nl4 + 0], sc[s2][nl4 + 1], sc[s2][nl4 + 2], sc[s2][nl4 + 3]};
      a += sw * pv;
    }
    f32x4 xv = *(const f32x4*)(xb + (size_t)c * Nn + n0 + nl4);
    *(f32x4*)(ob + (size_t)c * Nn + n0 + nl4) = xv + a;
  }
}

extern "C" void kernel_launch(void* const* d_in, const int* in_sizes, int n_in,
                              void* d_out, int out_size, void* d_ws, size_t ws_size,
                              hipStream_t stream) {
  const float* x = (const float*)d_in[0];
  const float* wq = (const float*)d_in[1];
  const float* wk = (const float*)d_in[2];
  const float* wv = (const float*)d_in[3];
  float* out = (float*)d_out;

  unsigned short* wqb = (unsigned short*)d_ws;
  unsigned short* wkb = wqb + Cn * Cn;
  unsigned short* wvb = wkb + Cn * Cn;
  unsigned short* Qt = wvb + Cn * Cn;
  unsigned short* Ksw = Qt + (size_t)Bn * Nn * Cn;
  unsigned short* Vsw = Ksw + (size_t)Bn * Nn * Cn;
  unsigned short* P = Vsw + (size_t)Bn * Nn * Cn;

  const size_t baseB = (size_t)(3 * Cn * Cn + 3 * (size_t)Bn * Nn * Cn) * 2;
  const size_t perSplitB = (size_t)Bn * Nn * Cn * 2 + (size_t)Bn * Nn * 2 * 4;

  int splits = 1;
  if (baseB + 4 * perSplitB <= ws_size) splits = 4;
  else if (baseB + 2 * perSplitB <= ws_size) splits = 2;

  float* ml = (float*)(P + (size_t)splits * Bn * Nn * Cn);

  hipLaunchKernelGGL(cvt_w, dim3(3 * Cn * Cn / 256), dim3(256), 0, stream, wq, wk, wv, wqb);
  hipLaunchKernelGGL(qkv_proj, dim3(Nn / 64, Bn, 3), dim3(256), 0, stream,
                     x, wqb, wkb, wvb, Qt, Ksw, Vsw);
  hipLaunchKernelGGL(attn_split, dim3(Bn * splits * 36), dim3(256), 0, stream,
                     Qt, Ksw, Vsw, P, ml, splits);
  hipLaunchKernelGGL(combine_k, dim3(Bn * Nn / 32), dim3(256), 0, stream,
                     x, P, ml, out, splits);
}

// Round 9
// 191.659 us; speedup vs baseline: 1.5930x; 1.5930x over previous
//
#include <hip/hip_runtime.h>
#include <hip/hip_bf16.h>

// SelfAttention: x[8,256,48,48] fp32; wq/wk/wv[256,256] fp32.
// out = x + attn(softmax(q^T k), v). B=8, C=256, N=2304. fp16 MFMA path.
//
// R8 post-mortem: register-direct streaming re-reads K/V per WAVE (1.4-2.7GB
// L2 traffic) and c-split duplicated that traffic. R9: LDS-stage the frag-
// ordered K/V chunk (linear 32KB memcpy via global_load_lds w=16, double
// buffered 64KB) shared by 4 waves; c-split keeps acc at 64 AGPR ->
// ~185 regs -> 2 waves/SIMD, 2 blocks/CU (barriers interleave).
// Each wave: full-C QK^T from LDS (dup across c-half pair, issue-only cost),
// softmax, PV for its 128 channels. All LDS reads are sequential b128.
//
// K_swz[kb][ks 16][hi 2][key 32][j 8]: short off = kb*8192+ks*512+hi*256+key*8+j
//   holds K[key of chunk kb][c = 16ks+8hi+j]   (A-frag for QK^T)
// V_swz[kb][ct 8][kh 2][hi 2][c 32][j 8]: off = kb*8192+ct*1024+kh*512+hi*256+c*8+j
//   holds V[c = 32ct+cloc][key = 16kh+8hi+j]   (A-frag = V^T for PV)
// ws: wq/wk/wv fp16 [65536 ea]; Qt [B*N*C] token-major; Ksw,Vsw [B*N*C];
//     P fp16 [splits][B][C][N] (per-split normalized O_s); ml f32 [splits][B][N][2].

#define DEVI __device__ __forceinline__

typedef _Float16 f16x8 __attribute__((ext_vector_type(8)));
typedef float f32x4 __attribute__((ext_vector_type(4)));
typedef float f32x16 __attribute__((ext_vector_type(16)));

constexpr int Bn = 8, Cn = 256, Nn = 48 * 48;   // 2304

DEVI unsigned short f2h(float f) {
  _Float16 h = (_Float16)f;
  return __builtin_bit_cast(unsigned short, h);
}
DEVI float h2f(unsigned short u) {
  return (float)__builtin_bit_cast(_Float16, u);
}
DEVI unsigned pk2(float a, float b) {           // pack 2 f32 -> f16x2 (RTZ)
  auto h = __builtin_amdgcn_cvt_pkrtz(a, b);
  return __builtin_bit_cast(unsigned, h);
}
DEVI void stage16(const unsigned short* g, unsigned short* l) {
  __builtin_amdgcn_global_load_lds(
      (const __attribute__((address_space(1))) void*)g,
      (__attribute__((address_space(3))) void*)l, 16, 0, 0);
}

#define MFMA16(a, b, c) __builtin_amdgcn_mfma_f32_16x16x32_f16((a), (b), (c), 0, 0, 0)
#define MFMA32(a, b, c) __builtin_amdgcn_mfma_f32_32x32x16_f16((a), (b), (c), 0, 0, 0)

__global__ __launch_bounds__(256) void cvt_w(const float* __restrict__ wq,
                                             const float* __restrict__ wk,
                                             const float* __restrict__ wv,
                                             unsigned short* __restrict__ o) {
  int idx = blockIdx.x * 256 + threadIdx.x;     // 3*65536 total
  const float* s = (idx < Cn * Cn) ? wq : (idx < 2 * Cn * Cn) ? wk : wv;
  o[idx] = f2h(s[idx & (Cn * Cn - 1)]);
}

// ---------------- QKV projection ----------------
// grid (N/64, B, 3), 256 thr (4 waves, 16 tokens each). z: 0=Q 1=K 2=V.
// 16x16x32 frags: A/B lane l: row/col=l&15, k=8*(l>>4)+j. C/D: col=l&15, row=4*(l>>4)+r.
__global__ __launch_bounds__(256) void qkv_proj(
    const float* __restrict__ x,
    const unsigned short* __restrict__ wqb, const unsigned short* __restrict__ wkb,
    const unsigned short* __restrict__ wvb,
    unsigned short* __restrict__ Qt, unsigned short* __restrict__ Ksw,
    unsigned short* __restrict__ Vsw) {
  __shared__ unsigned short xT[64][264];        // [token][c], +8 pad
  const int tid = threadIdx.x;
  const int n0 = blockIdx.x * 64;
  const int b = blockIdx.y;
  const int z = blockIdx.z;
  const float* xb = x + (size_t)b * Cn * Nn;
  {
    int cbase = tid >> 4;
    int nn = (tid & 15) * 4;
#pragma unroll
    for (int it = 0; it < 16; ++it) {
      int c = cbase + 16 * it;
      float4 v = *(const float4*)(xb + (size_t)c * Nn + n0 + nn);
      xT[nn + 0][c] = f2h(v.x);
      xT[nn + 1][c] = f2h(v.y);
      xT[nn + 2][c] = f2h(v.z);
      xT[nn + 3][c] = f2h(v.w);
    }
  }
  __syncthreads();
  const int lane = tid & 63, w = tid >> 6;
  const int i = lane & 15, g = lane >> 4;
  f16x8 xf[8];                                  // x^T frags
#pragma unroll
  for (int ks = 0; ks < 8; ++ks)
    xf[ks] = *(const f16x8*)(&xT[w * 16 + i][32 * ks + 8 * g]);

  const int kb0 = (n0 >> 5) + (w >> 1);         // 32-token chunk id
  if (z == 0) {                                 // Q -> token-major [N][C]
    const size_t tokbase = (size_t)b * Nn + n0 + w * 16;
    for (int ot = 0; ot < 16; ++ot) {
      f32x4 acc = {0.f, 0.f, 0.f, 0.f};
      const unsigned short* wr = wqb + (ot * 16 + i) * Cn + 8 * g;
#pragma unroll
      for (int ks = 0; ks < 8; ++ks)
        acc = MFMA16(xf[ks], *(const f16x8*)(wr + 32 * ks), acc);
#pragma unroll
      for (int r = 0; r < 4; ++r)
        Qt[(tokbase + 4 * g + r) * Cn + ot * 16 + i] = f2h(acc[r]);
    }
  } else if (z == 1) {                          // K -> frag-swizzled
    // acc[r] = K[tok = n0+w16+4g+r][c = ot*16+i]
    unsigned short* kout = Ksw + (size_t)b * Nn * Cn + (size_t)kb0 * 8192
                         + ((i >> 3) & 1) * 256 + (i & 7);
    const int keyb = (w & 1) * 16 + 4 * g;      // + r
    for (int ot = 0; ot < 16; ++ot) {
      f32x4 acc = {0.f, 0.f, 0.f, 0.f};
      const unsigned short* wr = wkb + (ot * 16 + i) * Cn + 8 * g;
#pragma unroll
      for (int ks = 0; ks < 8; ++ks)
        acc = MFMA16(xf[ks], *(const f16x8*)(wr + 32 * ks), acc);
#pragma unroll
      for (int r = 0; r < 4; ++r)
        kout[ot * 512 + (keyb + r) * 8] = f2h(acc[r]);
    }
  } else {                                      // V -> frag-swizzled (V^T A-frags)
    // acc[r] = V[c = ot*16+4g+r][tok = n0+w16+i]
    unsigned short* vout = Vsw + (size_t)b * Nn * Cn + (size_t)kb0 * 8192
                         + (w & 1) * 512 + ((i >> 3) & 1) * 256 + (i & 7);
    for (int ot = 0; ot < 16; ++ot) {
      f32x4 acc = {0.f, 0.f, 0.f, 0.f};
      const unsigned short* wr = wvb + (ot * 16 + i) * Cn + 8 * g;
#pragma unroll
      for (int ks = 0; ks < 8; ++ks)
        acc = MFMA16(*(const f16x8*)(wr + 32 * ks), xf[ks], acc);
#pragma unroll
      for (int r = 0; r < 4; ++r) {
        int c = ot * 16 + 4 * g + r;
        vout[(c >> 5) * 1024 + (c & 31) * 8] = f2h(acc[r]);
      }
    }
  }
}

// ---------------- flash attention: split-K, LDS-staged, c-split ------------
// grid Bn*splits*36, 256 thr = 4 waves = 2 q-tiles(32q) x 2 c-halves(128c).
// LDS 64KB: 2 bufs x (K 16KB | V 16KB), frag-ordered (linear copy of Ksw/Vsw
// chunk). Swapped S = mfma32(Kfrag, Qfrag): lane query=l&31, keys
// (r&3)+8(r>>2)+4hi. Full-C QK^T per wave; PV for own 128 channels.
__global__ __launch_bounds__(256, 2) void attn_split(
    const unsigned short* __restrict__ Qt, const unsigned short* __restrict__ Ksw,
    const unsigned short* __restrict__ Vsw,
    unsigned short* __restrict__ P, float* __restrict__ ml, int splits) {
  __shared__ unsigned short smem[32768];        // 64 KB
  const int nblk = gridDim.x;                   // divisible by 8
  const int cpx = nblk >> 3;
  const int swz = (blockIdx.x & 7) * cpx + (blockIdx.x >> 3);  // XCD chunked
  const int per_b = splits * 36;
  const int b = swz / per_b;
  const int rem = swz - b * per_b;
  const int s = rem / 36;
  const int qt = rem - s * 36;
  const int n0 = qt * 64;
  const int kn = Nn / splits;
  const int kb0 = (s * kn) >> 5;                // first 32-key chunk id
  const int NT = kn / 32;

  const int tid = threadIdx.x, lane = tid & 63, w = tid >> 6;
  const int q = lane & 31, hi = lane >> 5;
  const int qtile = w & 1, chalf = w >> 1;
  const int q0 = n0 + qtile * 32;

  const unsigned short* Kc = Ksw + (size_t)b * Nn * Cn + (size_t)tid * 8;
  const unsigned short* Vc = Vsw + (size_t)b * Nn * Cn + (size_t)tid * 8;

  auto stage = [&](int kbid, int buf) {         // linear 32KB chunk copy
    unsigned short* Kd = smem + buf * 16384 + w * 512;
    const unsigned short* Ks = Kc + (size_t)kbid * 8192;
    const unsigned short* Vs = Vc + (size_t)kbid * 8192;
#pragma unroll
    for (int c4 = 0; c4 < 4; ++c4) {
      stage16(Ks + c4 * 2048, Kd + c4 * 2048);
      stage16(Vs + c4 * 2048, Kd + 8192 + c4 * 2048);
    }
  };

  stage(kb0, 0);                                // prologue

  // resident Q B-frags: lane: query=q, c = 16*ks + 8*hi + j (overlaps staging)
  const unsigned short* Qb = Qt + ((size_t)b * Nn + q0 + q) * Cn + 8 * hi;
  f16x8 qf[16];
#pragma unroll
  for (int ks = 0; ks < 16; ++ks) qf[ks] = *(const f16x8*)(Qb + 16 * ks);

  f32x16 acc[4];                                // channels chalf*128 .. +128
#pragma unroll
  for (int ct = 0; ct < 4; ++ct) acc[ct] = (f32x16)(0.f);
  float m = -1e30f, lsum = 0.f;

  __syncthreads();                              // buf0 ready (drains vmcnt)

  int cur = 0;
  for (int t = 0; t < NT; ++t) {
    if (t + 1 < NT) stage(kb0 + t + 1, cur ^ 1);

    const char* KsB = (const char*)smem + cur * 32768;
    const char* VsB = KsB + 16384;
    const int lo = hi * 512 + q * 16;           // lane offset within frag row

    // ---- QK^T: d[key][query], 2 independent 8-MFMA chains over c=256 ----
    f32x16 da = (f32x16)(0.f), db = (f32x16)(0.f);
#pragma unroll
    for (int ks = 0; ks < 8; ++ks) {
      da = MFMA32(*(const f16x8*)(KsB + ks * 1024 + lo), qf[ks], da);
      db = MFMA32(*(const f16x8*)(KsB + (ks + 8) * 1024 + lo), qf[ks + 8], db);
    }
    f32x16 d = da + db;

    // ---- online softmax: lane owns query q, 16 scores ----
    float mx = d[0];
#pragma unroll
    for (int r = 1; r < 16; ++r) mx = fmaxf(mx, d[r]);
    mx = fmaxf(mx, __shfl_xor(mx, 32));         // full 32-key max
    if (__any(mx > m + 8.f)) {                  // defer-max (THR=8)
      float mnew = fmaxf(m, mx);
      float alpha = __expf(m - mnew);
      m = mnew;
      lsum *= alpha;
#pragma unroll
      for (int ct = 0; ct < 4; ++ct)
#pragma unroll
        for (int r = 0; r < 16; ++r) acc[ct][r] *= alpha;
    }
    float p[16];
#pragma unroll
    for (int r = 0; r < 16; ++r) p[r] = __expf(d[r] - m);
    float cs = 0.f;
#pragma unroll
    for (int r = 0; r < 16; ++r) cs += p[r];
    cs += __shfl_xor(cs, 32);
    lsum += cs;

    // ---- P -> B-frags (keys 0..15 | 16..31), half-wave exchange ----
    unsigned A0 = pk2(p[0], p[1]), A1 = pk2(p[2], p[3]);
    unsigned A2 = pk2(p[4], p[5]), A3 = pk2(p[6], p[7]);
    unsigned A4 = pk2(p[8], p[9]), A5 = pk2(p[10], p[11]);
    unsigned A6 = pk2(p[12], p[13]), A7 = pk2(p[14], p[15]);
    unsigned s0 = __shfl_xor(A0, 32), s1 = __shfl_xor(A1, 32);
    unsigned s2 = __shfl_xor(A2, 32), s3 = __shfl_xor(A3, 32);
    unsigned s4 = __shfl_xor(A4, 32), s5 = __shfl_xor(A5, 32);
    unsigned s6 = __shfl_xor(A6, 32), s7 = __shfl_xor(A7, 32);
    union { unsigned u[4]; f16x8 v; } pb0, pb1;
    pb0.u[0] = hi ? s2 : A0;  pb0.u[1] = hi ? s3 : A1;
    pb0.u[2] = hi ? A2 : s0;  pb0.u[3] = hi ? A3 : s1;
    pb1.u[0] = hi ? s6 : A4;  pb1.u[1] = hi ? s7 : A5;
    pb1.u[2] = hi ? A6 : s4;  pb1.u[3] = hi ? A7 : s5;

    // ---- PV: 4 c-tiles of this wave's c-half; sequential LDS frag reads ----
#pragma unroll
    for (int ct = 0; ct < 4; ++ct) {
      const int ctg = chalf * 4 + ct;
      f16x8 v0 = *(const f16x8*)(VsB + ctg * 2048 + lo);
      f16x8 v1 = *(const f16x8*)(VsB + ctg * 2048 + 1024 + lo);
      acc[ct] = MFMA32(v0, pb0.v, acc[ct]);
      acc[ct] = MFMA32(v1, pb1.v, acc[ct]);
    }
    __syncthreads();                            // next buf staged + cur free
    cur ^= 1;
  }

  // ---- epilogue: O_s = acc/lsum -> fp16; c = 32ctg + (r&3)+8*(r>>2)+4hi ----
  const float rl = 1.f / lsum;
  unsigned short* Pb = P + (size_t)(s * Bn + b) * Cn * Nn;
#pragma unroll
  for (int ct = 0; ct < 4; ++ct)
#pragma unroll
    for (int r = 0; r < 16; ++r) {
      int c = 32 * (chalf * 4 + ct) + (r & 3) + 8 * (r >> 2) + 4 * hi;
      Pb[(size_t)c * Nn + q0 + q] = f2h(acc[ct][r] * rl);
    }
  if (!hi && !chalf)
    *(float2*)&ml[((size_t)(s * Bn + b) * Nn + q0 + q) * 2] = make_float2(m, lsum);
}

// ---------------- combine partials + residual ----------------
// out = x + sum_s w_s * O_s,  w_s = exp(m_s - M) * l_s / sum(exp(m_s-M) l_s).
__global__ __launch_bounds__(256) void combine_k(
    const float* __restrict__ x, const unsigned short* __restrict__ P,
    const float* __restrict__ ml, float* __restrict__ out, int splits) {
  __shared__ float sc[4][32];
  const int tpb = Nn / 32;                      // 72
  const int b = blockIdx.x / tpb;
  const int n0 = (blockIdx.x - b * tpb) * 32;
  const int t = threadIdx.x;
  if (t < 32) {
    const int n = n0 + t;
    const size_t sstr = (size_t)Bn * Nn * 2;
    const float* mlb = ml + ((size_t)b * Nn + n) * 2;
    float m0 = mlb[0], l0 = mlb[1];
    float m1 = -1e30f, l1 = 0.f, m2 = -1e30f, l2 = 0.f, m3 = -1e30f, l3 = 0.f;
    if (splits > 1) { m1 = mlb[sstr]; l1 = mlb[sstr + 1]; }
    if (splits > 2) { m2 = mlb[2 * sstr]; l2 = mlb[2 * sstr + 1]; }
    if (splits > 3) { m3 = mlb[3 * sstr]; l3 = mlb[3 * sstr + 1]; }
    float M = fmaxf(fmaxf(m0, m1), fmaxf(m2, m3));
    float g0 = __expf(m0 - M) * l0, g1 = __expf(m1 - M) * l1;
    float g2 = __expf(m2 - M) * l2, g3 = __expf(m3 - M) * l3;
    float rden = 1.f / (g0 + g1 + g2 + g3);
    sc[0][t] = g0 * rden; sc[1][t] = g1 * rden;
    sc[2][t] = g2 * rden; sc[3][t] = g3 * rden;
  }
  __syncthreads();
  const int nl4 = (t & 7) * 4, c0 = t >> 3;
  const size_t pstr = (size_t)Bn * Cn * Nn;     // shorts per split
  const float* xb = x + (size_t)b * Cn * Nn;
  float* ob = out + (size_t)b * Cn * Nn;
#pragma unroll
  for (int k = 0; k < 8; ++k) {
    const int c = c0 + 32 * k;
    const unsigned short* Pp = P + ((size_t)b * Cn + c) * Nn + n0 + nl4;
    f32x4 a = {0.f, 0.f, 0.f, 0.f};
    for (int s2 = 0; s2 < splits; ++s2) {
      ushort4 ph = *(const ushort4*)(Pp + s2 * pstr);
      f32x4 pv = {h2f(ph.x), h2f(ph.y), h2f(ph.z), h2f(ph.w)};
      f32x4 sw = {sc[s2][nl4 + 0], sc[s2][nl4 + 1], sc[s2][nl4 + 2], sc[s2][nl4 + 3]};
      a += sw * pv;
    }
    f32x4 xv = *(const f32x4*)(xb + (size_t)c * Nn + n0 + nl4);
    *(f32x4*)(ob + (size_t)c * Nn + n0 + nl4) = xv + a;
  }
}

extern "C" void kernel_launch(void* const* d_in, const int* in_sizes, int n_in,
                              void* d_out, int out_size, void* d_ws, size_t ws_size,
                              hipStream_t stream) {
  const float* x = (const float*)d_in[0];
  const float* wq = (const float*)d_in[1];
  const float* wk = (const float*)d_in[2];
  const float* wv = (const float*)d_in[3];
  float* out = (float*)d_out;

  unsigned short* wqb = (unsigned short*)d_ws;
  unsigned short* wkb = wqb + Cn * Cn;
  unsigned short* wvb = wkb + Cn * Cn;
  unsigned short* Qt = wvb + Cn * Cn;
  unsigned short* Ksw = Qt + (size_t)Bn * Nn * Cn;
  unsigned short* Vsw = Ksw + (size_t)Bn * Nn * Cn;
  unsigned short* P = Vsw + (size_t)Bn * Nn * Cn;

  const size_t baseB = (size_t)(3 * Cn * Cn + 3 * (size_t)Bn * Nn * Cn) * 2;
  const size_t perSplitB = (size_t)Bn * Nn * Cn * 2 + (size_t)Bn * Nn * 2 * 4;

  int splits = 1;
  if (baseB + 4 * perSplitB <= ws_size) splits = 4;
  else if (baseB + 2 * perSplitB <= ws_size) splits = 2;

  float* ml = (float*)(P + (size_t)splits * Bn * Nn * Cn);

  hipLaunchKernelGGL(cvt_w, dim3(3 * Cn * Cn / 256), dim3(256), 0, stream, wq, wk, wv, wqb);
  hipLaunchKernelGGL(qkv_proj, dim3(Nn / 64, Bn, 3), dim3(256), 0, stream,
                     x, wqb, wkb, wvb, Qt, Ksw, Vsw);
  hipLaunchKernelGGL(attn_split, dim3(Bn * splits * 36), dim3(256), 0, stream,
                     Qt, Ksw, Vsw, P, ml, splits);
  hipLaunchKernelGGL(combine_k, dim3(Bn * Nn / 32), dim3(256), 0, stream,
                     x, P, ml, out, splits);
}